// Round 4
// baseline (9062.520 us; speedup 1.0000x reference)
//
#include <hip/hip_runtime.h>
#include <stdint.h>
#include <stddef.h>

#define T_   1024
#define BATCH 128
#define IN    512
#define HID  1024
#define OUTN  256

typedef unsigned short u16;
typedef __attribute__((ext_vector_type(8))) short short8;
typedef __attribute__((ext_vector_type(4))) float floatx4;

// Device-global scratch (d_ws size unknown). Fully rewritten every call.
__device__ u16 g_xbf[(size_t)BATCH * T_ * IN];     // x in bf16 [B*T][IN]
__device__ u16 g_kT[(size_t)HID * IN];             // kernel^T bf16 [H][IN]
// xp in chunk-fragment layout [T][8 bt][16 jt][1024]:
//   chunk idx = (j*4+rr)*64 + lp  <->  (row r=(lp>>4)*4+rr, col c=j*16+(lp&15))
__device__ u16 g_xp[(size_t)T_ * 8 * 16 * 1024];
// h ping-pong, same chunk-fragment layout: [2][8 bt][16 jt][1024]
__device__ u16 g_hc[(size_t)2 * 8 * 16 * 1024];
// per-(bt,jt,wave) step flags, one 64B line each: 8*16*4 = 512 lines
__device__ unsigned g_flag[8192];
__device__ unsigned g_done;

__device__ __forceinline__ u16 f2bf(float f) {
    uint32_t u = __builtin_bit_cast(uint32_t, f);
    u += 0x7fffu + ((u >> 16) & 1u);          // round-to-nearest-even
    return (u16)(u >> 16);
}
__device__ __forceinline__ float bf2f(u16 s) {
    uint32_t u = ((uint32_t)s) << 16;
    return __builtin_bit_cast(float, u);
}

__global__ void k_init() {
    for (int i = threadIdx.x; i < 8192; i += blockDim.x) g_flag[i] = 0u;
    if (threadIdx.x == 0) g_done = 0u;
}

// Convert x -> bf16 and kernel -> bf16 transposed (kT[n][k])
__global__ __launch_bounds__(256) void k_convert(const float* __restrict__ x,
                                                 const float* __restrict__ kern) {
    size_t i = (size_t)blockIdx.x * blockDim.x + threadIdx.x;
    size_t stride = (size_t)gridDim.x * blockDim.x;
    size_t n4 = (size_t)BATCH * T_ * IN / 4;
    for (size_t p = i; p < n4; p += stride) {
        float4 v = ((const float4*)x)[p];
        ushort4 o;
        o.x = f2bf(v.x); o.y = f2bf(v.y); o.z = f2bf(v.z); o.w = f2bf(v.w);
        ((ushort4*)g_xbf)[p] = o;
    }
    for (size_t p = i; p < (size_t)IN * HID; p += stride) {
        size_t k = p >> 10, n = p & 1023;        // read coalesced over n
        g_kT[n * IN + k] = f2bf(kern[p]);
    }
}

// xp = x @ kernel + bias   (M=131072, N=1024, K=512), bf16 MFMA, 128x128 tile.
// Epilogue scatters into chunk-fragment layout with NON-TEMPORAL stores so the
// 256MB xp stream does not occupy L3 (keeps scan's h/flag lines resident).
__global__ __launch_bounds__(256) void k_xp(const float* __restrict__ bias) {
    __shared__ u16 As[128][40];   // +8 pad: 2-way-only bank aliasing on b128 reads
    __shared__ u16 Bs[128][40];
    const int tid = threadIdx.x;
    const int bx = blockIdx.x & 7;       // n tile (8)
    const int by = blockIdx.x >> 3;      // m tile (1024)
    const int m0 = by * 128, n0 = bx * 128;
    const int lane = tid & 63, wave = tid >> 6;
    const int m_off = (wave & 1) * 64, n_off = (wave >> 1) * 64;
    const int sr = tid >> 1, skh = (tid & 1) * 16;

    floatx4 acc[4][4] = {};
    for (int k0 = 0; k0 < IN; k0 += 32) {
        const u16* ga = g_xbf + (size_t)(m0 + sr) * IN + k0 + skh;
        const u16* gb = g_kT  + (size_t)(n0 + sr) * IN + k0 + skh;
        int4 a0 = *(const int4*)ga, a1 = *(const int4*)(ga + 8);
        int4 b0 = *(const int4*)gb, b1 = *(const int4*)(gb + 8);
        __syncthreads();
        *(int4*)&As[sr][skh] = a0; *(int4*)&As[sr][skh + 8] = a1;
        *(int4*)&Bs[sr][skh] = b0; *(int4*)&Bs[sr][skh + 8] = b1;
        __syncthreads();
        short8 af[4], bf[4];
#pragma unroll
        for (int i = 0; i < 4; i++)
            af[i] = *(const short8*)&As[m_off + i * 16 + (lane & 15)][(lane >> 4) * 8];
#pragma unroll
        for (int j = 0; j < 4; j++)
            bf[j] = *(const short8*)&Bs[n_off + j * 16 + (lane & 15)][(lane >> 4) * 8];
#pragma unroll
        for (int i = 0; i < 4; i++)
#pragma unroll
            for (int j = 0; j < 4; j++)
                acc[i][j] = __builtin_amdgcn_mfma_f32_16x16x32_bf16(af[i], bf[j], acc[i][j], 0, 0, 0);
    }
    // D layout: col = lane&15, row = (lane>>4)*4 + reg  [m89-verified]
#pragma unroll
    for (int j = 0; j < 4; j++) {
        int n = n0 + n_off + j * 16 + (lane & 15);
        float bv = bias[n];
        int jt_x = n >> 6;
        int jx4 = ((n >> 4) & 3) * 4;
        int c15 = n & 15;
#pragma unroll
        for (int i = 0; i < 4; i++) {
#pragma unroll
            for (int rr = 0; rr < 4; rr++) {
                int m = m0 + m_off + i * 16 + (lane >> 4) * 4 + rr;
                int b = m >> 10, t = m & 1023;
                int r = b & 15;
                size_t idx = (((size_t)t * 8 + (b >> 4)) * 16 + jt_x) * 1024
                           + (size_t)((jx4 + (r & 3)) * 64 + (r >> 2) * 16 + c15);
                __builtin_nontemporal_store(f2bf(acc[i][j][rr] + bv), &g_xp[idx]);
            }
        }
    }
}

// Persistent scan: grid 256 = 128 workers (8 bt x 16 jt) + 128 HEATERS.
// Heaters keep every CU's VALU busy so the clock governor holds boost clocks
// (workers are ~98% latency-wait; without load the chip downclocks and every
// L3 hop inflates). 132KB LDS forces 1 WG/CU -> all 256 co-resident.
// Fabric: per-(jt,wave) flag lines, plain RELEASE store publish (no RMW chain),
// consumer wave polls only its 16 producer-wave lines (vector load + sleep).
// Overwrite safety: h-stores happen after the red-exchange barrier, and the 4
// waves' polls jointly cover all 64 flags >= t (same invariant as a full
// group barrier, aggregated by the intra-WG barrier).
#define SCAN_LDS (64 * 1032 * 2 + 4 * 4 * 4 * 64 * 4)
__global__ __launch_bounds__(256, 1) void k_scan(const float* __restrict__ R) {
    extern __shared__ char smem[];
    u16* Rs = (u16*)smem;                          // [64][1032] (k-pad 8 -> 2-way banks)
    float* red = (float*)(smem + 64 * 1032 * 2);   // [src][j][rr][64] cross-wave partials
    const int tid = threadIdx.x, lane = tid & 63, w = tid >> 6;
    const int g = blockIdx.x;

    if (g >= 128) {                                // ---- heater ----
        float a = 1.0f + (float)tid * 1e-7f;
        const float m = 1.0000001f, c = 1e-9f;
        long it = 0;
        while (true) {
#pragma unroll
            for (int u = 0; u < 256; ++u) a = __builtin_fmaf(a, m, c);
            asm volatile("" : "+v"(a));            // keep the chain live
            if (__hip_atomic_load(&g_done, __ATOMIC_RELAXED,
                                  __HIP_MEMORY_SCOPE_AGENT) >= 128u) break;
            if (++it > (1L << 21)) break;          // ~1s fuse
        }
        return;
    }

    const int bt = g & 7, jt = g >> 3;             // same-bt WGs -> same XCD (heuristic)
    const int n0 = jt * 64;

    // Load R columns n0..n0+63 into LDS as Rs[n_local][k]
    {
        const int rrow = tid >> 4;
        const int c4 = (tid & 15) * 4;
        for (int k = rrow; k < HID; k += 16) {
            float4 v = *(const float4*)&R[(size_t)k * HID + n0 + c4];
            Rs[(size_t)(c4 + 0) * 1032 + k] = f2bf(v.x);
            Rs[(size_t)(c4 + 1) * 1032 + k] = f2bf(v.y);
            Rs[(size_t)(c4 + 2) * 1032 + k] = f2bf(v.z);
            Rs[(size_t)(c4 + 3) * 1032 + k] = f2bf(v.w);
        }
    }
    __syncthreads();

    const int hi = lane >> 4;
    // consumer chunk offset (u16 units); add s*512 for k-substep s
    const int coff = (lane >> 5) * 256 + (lane & 3) * 64
                   + ((lane & 15) >> 2) * 16 + (hi & 1) * 8;
    // wave w consumes h cols [w*256,(w+1)*256) = chunks 4w..4w+3, produced by
    // WGs jt'=4w+a, waves b: flag lines bt*64 + w*16 + (4a+b)
    const unsigned* pflag = g_flag + ((size_t)(bt * 64 + w * 16 + (lane & 15)) << 4);
    unsigned* wflag = g_flag + ((size_t)((bt * 16 + jt) * 4 + w) << 4);

    long bail = 0;
    for (int t = 0; t < T_; ++t) {
        // xp prefetch: non-temporal (touch-once, keep out of L3), issued before
        // any polling so the latency hides under the wait
        const u16* xpb = g_xp + ((((size_t)t * 8 + bt) * 16 + jt) << 10) + w * 256 + lane;
        u16 xr0 = __builtin_nontemporal_load(xpb);
        u16 xr1 = __builtin_nontemporal_load(xpb + 64);
        u16 xr2 = __builtin_nontemporal_load(xpb + 128);
        u16 xr3 = __builtin_nontemporal_load(xpb + 192);

        floatx4 acc[4] = {};
        if (t > 0) {
            const unsigned tgt = (unsigned)t;
            unsigned v = __hip_atomic_load(pflag, __ATOMIC_RELAXED, __HIP_MEMORY_SCOPE_AGENT);
            while (!__all((int)(v >= tgt))) {
                __builtin_amdgcn_s_sleep(1);
                v = __hip_atomic_load(pflag, __ATOMIC_RELAXED, __HIP_MEMORY_SCOPE_AGENT);
                if (++bail > (1L << 24)) break;   // ~1s fuse (never hit if co-resident)
            }
            const u16* hb = g_hc + ((size_t)(t & 1) * 8 + bt) * 16384;
            union { unsigned long long u[2]; short8 v; } af[4][2];
            // all 8 16B frags issued up-front (1 wave/SIMD: hide latency via ILP)
#pragma unroll
            for (int cc = 0; cc < 4; ++cc) {
                const u16* cb = hb + (size_t)(4 * w + cc) * 1024 + coff;
#pragma unroll
                for (int s = 0; s < 2; ++s) {
                    const unsigned long long* q = (const unsigned long long*)(cb + s * 512);
                    af[cc][s].u[0] = __hip_atomic_load(q,     __ATOMIC_RELAXED, __HIP_MEMORY_SCOPE_AGENT);
                    af[cc][s].u[1] = __hip_atomic_load(q + 1, __ATOMIC_RELAXED, __HIP_MEMORY_SCOPE_AGENT);
                }
            }
#pragma unroll
            for (int cc = 0; cc < 4; ++cc)
#pragma unroll
                for (int s = 0; s < 2; ++s) {
                    const int kg = (4 * w + cc) * 64 + s * 32 + hi * 8;
#pragma unroll
                    for (int jj = 0; jj < 4; ++jj) {
                        short8 bfr = *(const short8*)&Rs[(size_t)(jj * 16 + (lane & 15)) * 1032 + kg];
                        acc[jj] = __builtin_amdgcn_mfma_f32_16x16x32_bf16(af[cc][s].v, bfr, acc[jj], 0, 0, 0);
                    }
                }
        }
        // cross-wave partial exchange (static indexing only; rule #20)
#pragma unroll
        for (int jj = 0; jj < 4; ++jj)
#pragma unroll
            for (int rr = 0; rr < 4; ++rr)
                red[((w * 4 + jj) * 4 + rr) * 64 + lane] = acc[jj][rr];
        __syncthreads();   // barrier1: also certifies all-64 flags >= t (4 waves' polls)
        // wave w reduces + activates + stores col-group j=w of own chunk
        u16* ob = g_hc + ((size_t)((t + 1) & 1) * 8 + bt) * 16384
                + (size_t)jt * 1024 + w * 256 + lane;
        const float xf[4] = { bf2f(xr0), bf2f(xr1), bf2f(xr2), bf2f(xr3) };
#pragma unroll
        for (int rr = 0; rr < 4; ++rr) {
            float s = xf[rr];
#pragma unroll
            for (int src = 0; src < 4; ++src)
                s += red[((src * 4 + w) * 4 + rr) * 64 + lane];
            s = fminf(fmaxf(s, -9.0f), 9.0f);
            float e = __expf(2.0f * s);                       // tanh = (e^2x-1)/(e^2x+1)
            float hv = (e - 1.0f) * __builtin_amdgcn_rcpf(e + 1.0f);
            __hip_atomic_store(ob + rr * 64, f2bf(hv),
                               __ATOMIC_RELAXED, __HIP_MEMORY_SCOPE_AGENT);
        }
        // per-wave publish: RELEASE store waits this wave's vmcnt(0) (wave-scoped
        // counter covers all 64 lanes' stores), then writes the flag line
        if (lane == 0)
            __hip_atomic_store(wflag, (unsigned)(t + 1), __ATOMIC_RELEASE,
                               __HIP_MEMORY_SCOPE_AGENT);
        __syncthreads();   // barrier2: protects red reuse next iteration
    }
    if (tid == 0)
        __hip_atomic_fetch_add(&g_done, 1u, __ATOMIC_RELAXED, __HIP_MEMORY_SCOPE_AGENT);
}

// out = h_last @ fc_w + fc_b   (128 x 256); h_1024 is in buffer 0 (1024&1==0)
__global__ __launch_bounds__(256) void k_final(const float* __restrict__ fcw,
                                               const float* __restrict__ fcb,
                                               float* __restrict__ out) {
    __shared__ float hsh[HID];
    int b = blockIdx.x, o = threadIdx.x;
    int bt = b >> 4, r = b & 15;
    const u16* hb = g_hc + (size_t)bt * 16384;
    for (int k = o; k < HID; k += 256) {
        int q = k >> 6, c = k & 63;
        int idx = q * 1024 + ((c >> 4) * 4 + (r & 3)) * 64 + (r >> 2) * 16 + (c & 15);
        hsh[k] = bf2f(__hip_atomic_load(hb + idx, __ATOMIC_RELAXED, __HIP_MEMORY_SCOPE_AGENT));
    }
    __syncthreads();
    float acc = fcb[o];
#pragma unroll 8
    for (int k = 0; k < HID; k++)
        acc += hsh[k] * fcw[(size_t)k * OUTN + o];
    out[(size_t)b * OUTN + o] = acc;
}

extern "C" void kernel_launch(void* const* d_in, const int* in_sizes, int n_in,
                              void* d_out, int out_size, void* d_ws, size_t ws_size,
                              hipStream_t stream) {
    const float* x    = (const float*)d_in[0];
    const float* kern = (const float*)d_in[1];
    const float* R    = (const float*)d_in[2];
    const float* bias = (const float*)d_in[3];
    const float* fcw  = (const float*)d_in[4];
    const float* fcb  = (const float*)d_in[5];
    float* out = (float*)d_out;

    k_init<<<1, 256, 0, stream>>>();
    k_convert<<<4096, 256, 0, stream>>>(x, kern);
    k_xp<<<8192, 256, 0, stream>>>(bias);
    (void)hipFuncSetAttribute((const void*)k_scan,
                              hipFuncAttributeMaxDynamicSharedMemorySize, SCAN_LDS);
    k_scan<<<256, 256, SCAN_LDS, stream>>>(R);
    k_final<<<128, 256, 0, stream>>>(fcw, fcb, out);
}

// Round 5
// 7643.176 us; speedup vs baseline: 1.1857x; 1.1857x over previous
//
#include <hip/hip_runtime.h>
#include <stdint.h>
#include <stddef.h>

#define T_   1024
#define BATCH 128
#define IN    512
#define HID  1024
#define OUTN  256

typedef unsigned short u16;
typedef __attribute__((ext_vector_type(8))) short short8;
typedef __attribute__((ext_vector_type(4))) float floatx4;

// Device-global scratch (d_ws size unknown). Fully rewritten every call.
__device__ u16 g_xbf[(size_t)BATCH * T_ * IN];     // x in bf16 [B*T][IN]
__device__ u16 g_kT[(size_t)HID * IN];             // kernel^T bf16 [H][IN]
// xp in chunk-fragment layout [T][8 bt][16 jt][1024]:
//   chunk idx = (j*4+rr)*64 + lp  <->  (row r=(lp>>4)*4+rr, col c=j*16+(lp&15))
__device__ u16 g_xp[(size_t)T_ * 8 * 16 * 1024];
// h ping-pong as TAGGED WORDS: {bf16 h in hi16 | step tag in lo16}
// [2][8 bt][16 chunk][1024 words] = 1MB. The store IS the publish.
__device__ unsigned g_hw[(size_t)2 * 8 * 16 * 1024];

__device__ __forceinline__ u16 f2bf(float f) {
    uint32_t u = __builtin_bit_cast(uint32_t, f);
    u += 0x7fffu + ((u >> 16) & 1u);          // round-to-nearest-even
    return (u16)(u >> 16);
}
__device__ __forceinline__ float bf2f(u16 s) {
    uint32_t u = ((uint32_t)s) << 16;
    return __builtin_bit_cast(float, u);
}

// Zero h tags each call (graph replay!) so stale tags from the previous call
// can never match this call's targets (tags this call are 1..1024).
__global__ __launch_bounds__(256) void k_init() {
    size_t i = (size_t)blockIdx.x * blockDim.x + threadIdx.x;   // 65536 threads
    ((uint4*)g_hw)[i] = uint4{0u, 0u, 0u, 0u};                  // 262144 words
}

// Convert x -> bf16 and kernel -> bf16 transposed (kT[n][k])
__global__ __launch_bounds__(256) void k_convert(const float* __restrict__ x,
                                                 const float* __restrict__ kern) {
    size_t i = (size_t)blockIdx.x * blockDim.x + threadIdx.x;
    size_t stride = (size_t)gridDim.x * blockDim.x;
    size_t n4 = (size_t)BATCH * T_ * IN / 4;
    for (size_t p = i; p < n4; p += stride) {
        float4 v = ((const float4*)x)[p];
        ushort4 o;
        o.x = f2bf(v.x); o.y = f2bf(v.y); o.z = f2bf(v.z); o.w = f2bf(v.w);
        ((ushort4*)g_xbf)[p] = o;
    }
    for (size_t p = i; p < (size_t)IN * HID; p += stride) {
        size_t k = p >> 10, n = p & 1023;        // read coalesced over n
        g_kT[n * IN + k] = f2bf(kern[p]);
    }
}

// xp = x @ kernel + bias   (M=131072, N=1024, K=512), bf16 MFMA, 128x128 tile.
// Epilogue scatters into the chunk-fragment layout the scan consumes.
__global__ __launch_bounds__(256) void k_xp(const float* __restrict__ bias) {
    __shared__ u16 As[128][40];   // +8 pad: 2-way-only bank aliasing on b128 reads
    __shared__ u16 Bs[128][40];
    const int tid = threadIdx.x;
    const int bx = blockIdx.x & 7;       // n tile (8)
    const int by = blockIdx.x >> 3;      // m tile (1024)
    const int m0 = by * 128, n0 = bx * 128;
    const int lane = tid & 63, wave = tid >> 6;
    const int m_off = (wave & 1) * 64, n_off = (wave >> 1) * 64;
    const int sr = tid >> 1, skh = (tid & 1) * 16;

    floatx4 acc[4][4] = {};
    for (int k0 = 0; k0 < IN; k0 += 32) {
        const u16* ga = g_xbf + (size_t)(m0 + sr) * IN + k0 + skh;
        const u16* gb = g_kT  + (size_t)(n0 + sr) * IN + k0 + skh;
        int4 a0 = *(const int4*)ga, a1 = *(const int4*)(ga + 8);
        int4 b0 = *(const int4*)gb, b1 = *(const int4*)(gb + 8);
        __syncthreads();
        *(int4*)&As[sr][skh] = a0; *(int4*)&As[sr][skh + 8] = a1;
        *(int4*)&Bs[sr][skh] = b0; *(int4*)&Bs[sr][skh + 8] = b1;
        __syncthreads();
        short8 af[4], bf[4];
#pragma unroll
        for (int i = 0; i < 4; i++)
            af[i] = *(const short8*)&As[m_off + i * 16 + (lane & 15)][(lane >> 4) * 8];
#pragma unroll
        for (int j = 0; j < 4; j++)
            bf[j] = *(const short8*)&Bs[n_off + j * 16 + (lane & 15)][(lane >> 4) * 8];
#pragma unroll
        for (int i = 0; i < 4; i++)
#pragma unroll
            for (int j = 0; j < 4; j++)
                acc[i][j] = __builtin_amdgcn_mfma_f32_16x16x32_bf16(af[i], bf[j], acc[i][j], 0, 0, 0);
    }
    // D layout: col = lane&15, row = (lane>>4)*4 + reg  [m89-verified]
#pragma unroll
    for (int j = 0; j < 4; j++) {
        int n = n0 + n_off + j * 16 + (lane & 15);
        float bv = bias[n];
        int jt_x = n >> 6;
        int jx4 = ((n >> 4) & 3) * 4;
        int c15 = n & 15;
#pragma unroll
        for (int i = 0; i < 4; i++) {
#pragma unroll
            for (int rr = 0; rr < 4; rr++) {
                int m = m0 + m_off + i * 16 + (lane >> 4) * 4 + rr;
                int b = m >> 10, t = m & 1023;
                int r = b & 15;
                size_t idx = (((size_t)t * 8 + (b >> 4)) * 16 + jt_x) * 1024
                           + (size_t)((jx4 + (r & 3)) * 64 + (r >> 2) * 16 + c15);
                g_xp[idx] = f2bf(acc[i][j][rr] + bv);
            }
        }
    }
}

// Persistent scan: 128 WGs = 8 bt-groups (16 rows) x 16 jt-chunks (64 cols).
// Sync protocol: TAG-IN-WORD. h element = {bf16 | tag}. Producer's data store
// IS the publish (word-atomic, relaxed). Consumer polls the h words it will
// consume; when all 64 tags match t, the data is already in registers —
// detect and load are ONE L3 round trip. No flags, no fences, no barriers
// across WGs. 2-buffer safety: WG in step t observed tags t-1 everywhere =>
// every producer's h_{t-2} reads retired before its tag-(t-1) store => the
// h_t overwrite of that buffer races nothing.
#define SCAN_LDS (64 * 1032 * 2 + 4 * 4 * 4 * 64 * 4)
__global__ __launch_bounds__(256, 1) void k_scan(const float* __restrict__ R) {
    extern __shared__ char smem[];
    u16* Rs = (u16*)smem;                          // [64][1032] (k-pad 8 -> 2-way banks)
    float* red = (float*)(smem + 64 * 1032 * 2);   // [src][j][rr][64] cross-wave partials
    const int tid = threadIdx.x, lane = tid & 63, w = tid >> 6;
    const int g = blockIdx.x, bt = g & 7, jt = g >> 3;   // same-bt WGs -> same XCD (RR heuristic)
    const int n0 = jt * 64;

    // Load R columns n0..n0+63 into LDS as Rs[n_local][k]
    {
        const int rrow = tid >> 4;
        const int c4 = (tid & 15) * 4;
        for (int k = rrow; k < HID; k += 16) {
            float4 v = *(const float4*)&R[(size_t)k * HID + n0 + c4];
            Rs[(size_t)(c4 + 0) * 1032 + k] = f2bf(v.x);
            Rs[(size_t)(c4 + 1) * 1032 + k] = f2bf(v.y);
            Rs[(size_t)(c4 + 2) * 1032 + k] = f2bf(v.z);
            Rs[(size_t)(c4 + 3) * 1032 + k] = f2bf(v.w);
        }
    }
    __syncthreads();

    const int hi = lane >> 4;
    // consumer element offset within a chunk (word units); +s*512 per k-substep
    const int coff = (lane >> 5) * 256 + (lane & 3) * 64
                   + ((lane & 15) >> 2) * 16 + (hi & 1) * 8;

    long bail = 0;
    for (int t = 0; t < T_; ++t) {
        // xp prefetch (4 coalesced 128B wave-loads; latency hides under the poll)
        const u16* xpb = g_xp + ((((size_t)t * 8 + bt) * 16 + jt) << 10) + w * 256 + lane;
        u16 xr0 = xpb[0], xr1 = xpb[64], xr2 = xpb[128], xr3 = xpb[192];

        floatx4 acc[4] = {};
        if (t > 0) {
            const unsigned tgt = (unsigned)t & 0xffffu;   // h_{t-1} carries tag t
            const unsigned* hb = g_hw + ((size_t)(t & 1) * 8 + bt) * 16384;
            // wave w consumes chunks 4w..4w+3 (its K-slice [w*256,(w+1)*256))
            const unsigned* cb0 = hb + (size_t)(4 * w + 0) * 1024 + coff;
            const unsigned* cb1 = hb + (size_t)(4 * w + 1) * 1024 + coff;
            const unsigned* cb2 = hb + (size_t)(4 * w + 2) * 1024 + coff;
            const unsigned* cb3 = hb + (size_t)(4 * w + 3) * 1024 + coff;
            unsigned long long q[4][2][4];     // all indices static after unroll
            while (1) {
#pragma unroll
                for (int cc = 0; cc < 4; ++cc) {
                    const unsigned* cb = (cc == 0) ? cb0 : (cc == 1) ? cb1
                                       : (cc == 2) ? cb2 : cb3;
#pragma unroll
                    for (int s = 0; s < 2; ++s) {
                        const unsigned long long* p =
                            (const unsigned long long*)(cb + s * 512);
#pragma unroll
                        for (int e = 0; e < 4; ++e)
                            q[cc][s][e] = __hip_atomic_load(p + e, __ATOMIC_RELAXED,
                                                            __HIP_MEMORY_SCOPE_AGENT);
                    }
                }
                unsigned bad = 0;
#pragma unroll
                for (int cc = 0; cc < 4; ++cc)
#pragma unroll
                    for (int s = 0; s < 2; ++s)
#pragma unroll
                        for (int e = 0; e < 4; ++e) {
                            unsigned long long v = q[cc][s][e];
                            bad |= ((unsigned)v ^ tgt) & 0xffffu;
                            bad |= ((unsigned)(v >> 32) ^ tgt) & 0xffffu;
                        }
                if (__all(bad == 0)) break;
                if (++bail > (1L << 21)) break;   // ~2s cumulative fuse
            }
            // pack hi16 halves -> bf16 frags, then MFMA
#pragma unroll
            for (int cc = 0; cc < 4; ++cc)
#pragma unroll
                for (int s = 0; s < 2; ++s) {
                    union { unsigned u[4]; short8 v; } pk;
#pragma unroll
                    for (int e = 0; e < 4; ++e) {
                        unsigned long long v = q[cc][s][e];
                        pk.u[e] = ((unsigned)v >> 16) |
                                  ((unsigned)(v >> 32) & 0xffff0000u);
                    }
                    const int kg = (4 * w + cc) * 64 + s * 32 + hi * 8;
#pragma unroll
                    for (int jj = 0; jj < 4; ++jj) {
                        short8 bfr = *(const short8*)&Rs[(size_t)(jj * 16 + (lane & 15)) * 1032 + kg];
                        acc[jj] = __builtin_amdgcn_mfma_f32_16x16x32_bf16(pk.v, bfr, acc[jj], 0, 0, 0);
                    }
                }
        }
        // cross-wave partial exchange (static indexing only; rule #20)
#pragma unroll
        for (int jj = 0; jj < 4; ++jj)
#pragma unroll
            for (int rr = 0; rr < 4; ++rr)
                red[((w * 4 + jj) * 4 + rr) * 64 + lane] = acc[jj][rr];
        __syncthreads();
        // wave w reduces + activates + stores col-group j=w of own chunk
        unsigned* ob = g_hw + ((size_t)((t + 1) & 1) * 8 + bt) * 16384
                     + (size_t)jt * 1024 + w * 256 + lane;
        const unsigned otag = (unsigned)(t + 1) & 0xffffu;
        const float xf[4] = { bf2f(xr0), bf2f(xr1), bf2f(xr2), bf2f(xr3) };
#pragma unroll
        for (int rr = 0; rr < 4; ++rr) {
            float s = xf[rr];
#pragma unroll
            for (int src = 0; src < 4; ++src)
                s += red[((src * 4 + w) * 4 + rr) * 64 + lane];
            s = fminf(fmaxf(s, -9.0f), 9.0f);
            float e = __expf(2.0f * s);                       // tanh = (e^2x-1)/(e^2x+1)
            float hv = (e - 1.0f) * __builtin_amdgcn_rcpf(e + 1.0f);
            unsigned word = ((unsigned)f2bf(hv) << 16) | otag;
            __hip_atomic_store(ob + rr * 64, word,
                               __ATOMIC_RELAXED, __HIP_MEMORY_SCOPE_AGENT);
        }
        __syncthreads();   // protects red reuse next iteration
    }
}

// out = h_last @ fc_w + fc_b   (128 x 256); h_1024 is in buffer 0 (1024&1==0)
__global__ __launch_bounds__(256) void k_final(const float* __restrict__ fcw,
                                               const float* __restrict__ fcb,
                                               float* __restrict__ out) {
    __shared__ float hsh[HID];
    int b = blockIdx.x, o = threadIdx.x;
    int bt = b >> 4, r = b & 15;
    const unsigned* hb = g_hw + (size_t)bt * 16384;
    for (int k = o; k < HID; k += 256) {
        int q = k >> 6, c = k & 63;
        int idx = q * 1024 + ((c >> 4) * 4 + (r & 3)) * 64 + (r >> 2) * 16 + (c & 15);
        unsigned word = __hip_atomic_load(hb + idx, __ATOMIC_RELAXED,
                                          __HIP_MEMORY_SCOPE_AGENT);
        hsh[k] = __builtin_bit_cast(float, word & 0xffff0000u);
    }
    __syncthreads();
    float acc = fcb[o];
#pragma unroll 8
    for (int k = 0; k < HID; k++)
        acc += hsh[k] * fcw[(size_t)k * OUTN + o];
    out[(size_t)b * OUTN + o] = acc;
}

extern "C" void kernel_launch(void* const* d_in, const int* in_sizes, int n_in,
                              void* d_out, int out_size, void* d_ws, size_t ws_size,
                              hipStream_t stream) {
    const float* x    = (const float*)d_in[0];
    const float* kern = (const float*)d_in[1];
    const float* R    = (const float*)d_in[2];
    const float* bias = (const float*)d_in[3];
    const float* fcw  = (const float*)d_in[4];
    const float* fcb  = (const float*)d_in[5];
    float* out = (float*)d_out;

    k_init<<<256, 256, 0, stream>>>();
    k_convert<<<4096, 256, 0, stream>>>(x, kern);
    k_xp<<<8192, 256, 0, stream>>>(bias);
    (void)hipFuncSetAttribute((const void*)k_scan,
                              hipFuncAttributeMaxDynamicSharedMemorySize, SCAN_LDS);
    k_scan<<<128, 256, SCAN_LDS, stream>>>(R);
    k_final<<<128, 256, 0, stream>>>(fcw, fcb, out);
}

// Round 6
// 5270.774 us; speedup vs baseline: 1.7194x; 1.4501x over previous
//
#include <hip/hip_runtime.h>
#include <stdint.h>
#include <stddef.h>

#define T_   1024
#define BATCH 128
#define IN    512
#define HID  1024
#define OUTN  256
#define PROBE_ITERS 256

typedef unsigned short u16;
typedef __attribute__((ext_vector_type(8))) short short8;
typedef __attribute__((ext_vector_type(4))) float floatx4;

// Device-global scratch (d_ws size unknown). Fully rewritten every call.
__device__ u16 g_xbf[(size_t)BATCH * T_ * IN];     // x in bf16 [B*T][IN]
__device__ u16 g_kT[(size_t)HID * IN];             // kernel^T bf16 [H][IN]
// xp in chunk-fragment layout [T][8 bt][16 jt][1024]:
//   chunk idx = (j*4+rr)*64 + lp  <->  (row r=(lp>>4)*4+rr, col c=j*16+(lp&15))
__device__ u16 g_xp[(size_t)T_ * 8 * 16 * 1024];
// h ping-pong, chunk-fragment layout: [2][8 bt][16 jt][1024]
__device__ u16 g_h[(size_t)2 * 8 * 16 * 1024];
// DIGEST LINES: one 64B line per bt-group, word jt = last step WG(bt,jt)
// published. Plain per-word stores (parallel, no RMW serialization);
// consumers read the whole line with one coalesced 64B load.
__device__ unsigned g_sync[8][32];      // 128B-padded per bt
// probe scratch
__device__ unsigned g_psync[8][32];
__device__ u16 g_pd[(size_t)2 * 8 * 16 * 1024];

__device__ __forceinline__ u16 f2bf(float f) {
    uint32_t u = __builtin_bit_cast(uint32_t, f);
    u += 0x7fffu + ((u >> 16) & 1u);          // round-to-nearest-even
    return (u16)(u >> 16);
}
__device__ __forceinline__ float bf2f(u16 s) {
    uint32_t u = ((uint32_t)s) << 16;
    return __builtin_bit_cast(float, u);
}

__global__ void k_init() {
    int i = threadIdx.x;                       // 256 threads, 512 words
    ((unsigned*)g_sync)[i]  = 0u;
    ((unsigned*)g_psync)[i] = 0u;
}

// Convert x -> bf16 and kernel -> bf16 transposed (kT[n][k])
__global__ __launch_bounds__(256) void k_convert(const float* __restrict__ x,
                                                 const float* __restrict__ kern) {
    size_t i = (size_t)blockIdx.x * blockDim.x + threadIdx.x;
    size_t stride = (size_t)gridDim.x * blockDim.x;
    size_t n4 = (size_t)BATCH * T_ * IN / 4;
    for (size_t p = i; p < n4; p += stride) {
        float4 v = ((const float4*)x)[p];
        ushort4 o;
        o.x = f2bf(v.x); o.y = f2bf(v.y); o.z = f2bf(v.z); o.w = f2bf(v.w);
        ((ushort4*)g_xbf)[p] = o;
    }
    for (size_t p = i; p < (size_t)IN * HID; p += stride) {
        size_t k = p >> 10, n = p & 1023;        // read coalesced over n
        g_kT[n * IN + k] = f2bf(kern[p]);
    }
}

// xp = x @ kernel + bias   (M=131072, N=1024, K=512), bf16 MFMA, 128x128 tile.
__global__ __launch_bounds__(256) void k_xp(const float* __restrict__ bias) {
    __shared__ u16 As[128][40];   // +8 pad: 2-way-only bank aliasing on b128 reads
    __shared__ u16 Bs[128][40];
    const int tid = threadIdx.x;
    const int bx = blockIdx.x & 7;       // n tile (8)
    const int by = blockIdx.x >> 3;      // m tile (1024)
    const int m0 = by * 128, n0 = bx * 128;
    const int lane = tid & 63, wave = tid >> 6;
    const int m_off = (wave & 1) * 64, n_off = (wave >> 1) * 64;
    const int sr = tid >> 1, skh = (tid & 1) * 16;

    floatx4 acc[4][4] = {};
    for (int k0 = 0; k0 < IN; k0 += 32) {
        const u16* ga = g_xbf + (size_t)(m0 + sr) * IN + k0 + skh;
        const u16* gb = g_kT  + (size_t)(n0 + sr) * IN + k0 + skh;
        int4 a0 = *(const int4*)ga, a1 = *(const int4*)(ga + 8);
        int4 b0 = *(const int4*)gb, b1 = *(const int4*)(gb + 8);
        __syncthreads();
        *(int4*)&As[sr][skh] = a0; *(int4*)&As[sr][skh + 8] = a1;
        *(int4*)&Bs[sr][skh] = b0; *(int4*)&Bs[sr][skh + 8] = b1;
        __syncthreads();
        short8 af[4], bf[4];
#pragma unroll
        for (int i = 0; i < 4; i++)
            af[i] = *(const short8*)&As[m_off + i * 16 + (lane & 15)][(lane >> 4) * 8];
#pragma unroll
        for (int j = 0; j < 4; j++)
            bf[j] = *(const short8*)&Bs[n_off + j * 16 + (lane & 15)][(lane >> 4) * 8];
#pragma unroll
        for (int i = 0; i < 4; i++)
#pragma unroll
            for (int j = 0; j < 4; j++)
                acc[i][j] = __builtin_amdgcn_mfma_f32_16x16x32_bf16(af[i], bf[j], acc[i][j], 0, 0, 0);
    }
    // D layout: col = lane&15, row = (lane>>4)*4 + reg  [m89-verified]
#pragma unroll
    for (int j = 0; j < 4; j++) {
        int n = n0 + n_off + j * 16 + (lane & 15);
        float bv = bias[n];
        int jt_x = n >> 6;
        int jx4 = ((n >> 4) & 3) * 4;
        int c15 = n & 15;
#pragma unroll
        for (int i = 0; i < 4; i++) {
#pragma unroll
            for (int rr = 0; rr < 4; rr++) {
                int m = m0 + m_off + i * 16 + (lane >> 4) * 4 + rr;
                int b = m >> 10, t = m & 1023;
                int r = b & 15;
                size_t idx = (((size_t)t * 8 + (b >> 4)) * 16 + jt_x) * 1024
                           + (size_t)((jx4 + (r & 3)) * 64 + (r >> 2) * 16 + c15);
                g_xp[idx] = f2bf(acc[i][j][rr] + bv);
            }
        }
    }
}

// Persistent scan: 128 WGs = 8 bt-groups (16 rows) x 16 jt-chunks (64 cols).
// DIGEST-LINE protocol: publish = plain store of (t+1) into own word of the
// bt-group's 64B line (16 parallel word-stores, NO same-line RMW chain);
// poll = one coalesced 64B line load (lane&15) + s_sleep backoff.
// 2-buffer safety: flag(jt')==t means WG jt' finished its step-t MFMA (which
// consumed h_{t-1}) before storing h_t; a WG entering step t+1 observed all
// flags >= t, so overwriting buffer t&1 with h_{t+1} races nothing.
#define SCAN_LDS (64 * 1032 * 2 + 4 * 4 * 4 * 64 * 4)
__global__ __launch_bounds__(256, 1) void k_scan(const float* __restrict__ R) {
    extern __shared__ char smem[];
    u16* Rs = (u16*)smem;                          // [64][1032] (k-pad 8 -> 2-way banks)
    float* red = (float*)(smem + 64 * 1032 * 2);   // [src][j][rr][64] cross-wave partials
    const int tid = threadIdx.x, lane = tid & 63, w = tid >> 6;
    const int g = blockIdx.x, bt = g & 7, jt = g >> 3;   // same-bt WGs -> same XCD (RR heuristic)
    const int n0 = jt * 64;

    // Load R columns n0..n0+63 into LDS as Rs[n_local][k]
    {
        const int rrow = tid >> 4;
        const int c4 = (tid & 15) * 4;
        for (int k = rrow; k < HID; k += 16) {
            float4 v = *(const float4*)&R[(size_t)k * HID + n0 + c4];
            Rs[(size_t)(c4 + 0) * 1032 + k] = f2bf(v.x);
            Rs[(size_t)(c4 + 1) * 1032 + k] = f2bf(v.y);
            Rs[(size_t)(c4 + 2) * 1032 + k] = f2bf(v.z);
            Rs[(size_t)(c4 + 3) * 1032 + k] = f2bf(v.w);
        }
    }
    __syncthreads();

    const int hi = lane >> 4;
    // consumer chunk offset (u16 units); add s*512 for k-substep s
    const int coff = (lane >> 5) * 256 + (lane & 3) * 64
                   + ((lane & 15) >> 2) * 16 + (hi & 1) * 8;
    const unsigned* sline = &g_sync[bt][lane & 15];  // whole line, 4-way broadcast
    unsigned* myflag = &g_sync[bt][jt];

    long bail = 0;
    for (int t = 0; t < T_; ++t) {
        // xp prefetch (4 coalesced 128B wave-loads; latency hides under the poll)
        const u16* xpb = g_xp + ((((size_t)t * 8 + bt) * 16 + jt) << 10) + w * 256 + lane;
        u16 xr0 = xpb[0], xr1 = xpb[64], xr2 = xpb[128], xr3 = xpb[192];

        floatx4 acc[4] = {};
        if (t > 0) {
            const unsigned tgt = (unsigned)t;
            unsigned v = __hip_atomic_load(sline, __ATOMIC_RELAXED, __HIP_MEMORY_SCOPE_AGENT);
            while (!__all((int)(v >= tgt))) {
                __builtin_amdgcn_s_sleep(1);
                v = __hip_atomic_load(sline, __ATOMIC_RELAXED, __HIP_MEMORY_SCOPE_AGENT);
                if (++bail > (1L << 24)) break;   // fuse (never hit if co-resident)
            }
            const u16* hb = g_h + ((size_t)(t & 1) * 8 + bt) * 16384;
            union { unsigned long long u[2]; short8 v; } af[4][2];
            // K-split: wave w covers k in [w*256, w*256+256); 8 16B frags up-front
#pragma unroll
            for (int cc = 0; cc < 4; ++cc) {
                const u16* cb = hb + (size_t)(4 * w + cc) * 1024 + coff;
#pragma unroll
                for (int s = 0; s < 2; ++s) {
                    const unsigned long long* q = (const unsigned long long*)(cb + s * 512);
                    af[cc][s].u[0] = __hip_atomic_load(q,     __ATOMIC_RELAXED, __HIP_MEMORY_SCOPE_AGENT);
                    af[cc][s].u[1] = __hip_atomic_load(q + 1, __ATOMIC_RELAXED, __HIP_MEMORY_SCOPE_AGENT);
                }
            }
#pragma unroll
            for (int cc = 0; cc < 4; ++cc)
#pragma unroll
                for (int s = 0; s < 2; ++s) {
                    const int kg = (4 * w + cc) * 64 + s * 32 + hi * 8;
#pragma unroll
                    for (int jj = 0; jj < 4; ++jj) {
                        short8 bfr = *(const short8*)&Rs[(size_t)(jj * 16 + (lane & 15)) * 1032 + kg];
                        acc[jj] = __builtin_amdgcn_mfma_f32_16x16x32_bf16(af[cc][s].v, bfr, acc[jj], 0, 0, 0);
                    }
                }
        }
        // cross-wave partial exchange (static indexing only; rule #20)
#pragma unroll
        for (int jj = 0; jj < 4; ++jj)
#pragma unroll
            for (int rr = 0; rr < 4; ++rr)
                red[((w * 4 + jj) * 4 + rr) * 64 + lane] = acc[jj][rr];
        __syncthreads();
        // wave w reduces + activates + stores col-group j=w of own chunk
        u16* ob = g_h + ((size_t)((t + 1) & 1) * 8 + bt) * 16384
                + (size_t)jt * 1024 + w * 256 + lane;
        const float xf[4] = { bf2f(xr0), bf2f(xr1), bf2f(xr2), bf2f(xr3) };
#pragma unroll
        for (int rr = 0; rr < 4; ++rr) {
            float s = xf[rr];
#pragma unroll
            for (int src = 0; src < 4; ++src)
                s += red[((src * 4 + w) * 4 + rr) * 64 + lane];
            s = fminf(fmaxf(s, -9.0f), 9.0f);
            float e = __expf(2.0f * s);                       // tanh = (e^2x-1)/(e^2x+1)
            float hv = (e - 1.0f) * __builtin_amdgcn_rcpf(e + 1.0f);
            __hip_atomic_store(ob + rr * 64, f2bf(hv),
                               __ATOMIC_RELAXED, __HIP_MEMORY_SCOPE_AGENT);
        }
        __syncthreads();   // drains ALL waves' stores (vmcnt(0) before s_barrier)
        if (tid == 0)      // parallel per-word publish: no RMW serialization
            __hip_atomic_store(myflag, (unsigned)(t + 1),
                               __ATOMIC_RELAXED, __HIP_MEMORY_SCOPE_AGENT);
    }
}

// ---- PROBE 1: pure rendezvous, digest-line protocol, no data, no compute.
// dur/PROBE_ITERS = intrinsic sync period. Runs AFTER k_final (no interference).
__global__ __launch_bounds__(256, 1) void k_p1() {
    extern __shared__ char smem[];
    (void)smem;
    const int tid = threadIdx.x, lane = tid & 63;
    const int g = blockIdx.x, bt = g & 7, jt = g >> 3;
    const unsigned* sline = &g_psync[bt][lane & 15];
    unsigned* myflag = &g_psync[bt][jt];
    long bail = 0;
    for (int t = 0; t < PROBE_ITERS; ++t) {
        if (t > 0) {
            unsigned v = __hip_atomic_load(sline, __ATOMIC_RELAXED, __HIP_MEMORY_SCOPE_AGENT);
            while (!__all((int)(v >= (unsigned)t))) {
                __builtin_amdgcn_s_sleep(1);
                v = __hip_atomic_load(sline, __ATOMIC_RELAXED, __HIP_MEMORY_SCOPE_AGENT);
                if (++bail > (1L << 22)) break;
            }
        }
        __syncthreads();
        if (tid == 0)
            __hip_atomic_store(myflag, (unsigned)(t + 1),
                               __ATOMIC_RELAXED, __HIP_MEMORY_SCOPE_AGENT);
        __syncthreads();
    }
}

// ---- PROBE 2: rendezvous + exact h-transfer pattern (32KB load + 2KB store
// per WG per iter), no MFMA/LDS/tanh. dur-P1 = data-hop add-on.
__global__ __launch_bounds__(256, 1) void k_p2() {
    extern __shared__ char smem[];
    (void)smem;
    const int tid = threadIdx.x, lane = tid & 63, w = tid >> 6;
    const int g = blockIdx.x, bt = g & 7, jt = g >> 3;
    const int hi = lane >> 4;
    const int coff = (lane >> 5) * 256 + (lane & 3) * 64
                   + ((lane & 15) >> 2) * 16 + (hi & 1) * 8;
    const unsigned* sline = &g_psync[bt][16 + (lane & 15)];   // second half-line set
    unsigned* myflag = &g_psync[bt][16 + jt];
    long bail = 0;
    unsigned long long keep = 0;
    for (int t = 0; t < PROBE_ITERS; ++t) {
        if (t > 0) {
            unsigned v = __hip_atomic_load(sline, __ATOMIC_RELAXED, __HIP_MEMORY_SCOPE_AGENT);
            while (!__all((int)(v >= (unsigned)t))) {
                __builtin_amdgcn_s_sleep(1);
                v = __hip_atomic_load(sline, __ATOMIC_RELAXED, __HIP_MEMORY_SCOPE_AGENT);
                if (++bail > (1L << 22)) break;
            }
            const u16* hb = g_pd + ((size_t)(t & 1) * 8 + bt) * 16384;
#pragma unroll
            for (int cc = 0; cc < 4; ++cc) {
                const u16* cb = hb + (size_t)(4 * w + cc) * 1024 + coff;
#pragma unroll
                for (int s = 0; s < 2; ++s) {
                    const unsigned long long* q = (const unsigned long long*)(cb + s * 512);
                    keep ^= __hip_atomic_load(q,     __ATOMIC_RELAXED, __HIP_MEMORY_SCOPE_AGENT);
                    keep ^= __hip_atomic_load(q + 1, __ATOMIC_RELAXED, __HIP_MEMORY_SCOPE_AGENT);
                }
            }
        }
        __syncthreads();
        u16* ob = g_pd + ((size_t)((t + 1) & 1) * 8 + bt) * 16384
                + (size_t)jt * 1024 + w * 256 + lane;
#pragma unroll
        for (int rr = 0; rr < 4; ++rr)
            __hip_atomic_store(ob + rr * 64, (u16)(keep + rr),
                               __ATOMIC_RELAXED, __HIP_MEMORY_SCOPE_AGENT);
        __syncthreads();
        if (tid == 0)
            __hip_atomic_store(myflag, (unsigned)(t + 1),
                               __ATOMIC_RELAXED, __HIP_MEMORY_SCOPE_AGENT);
    }
    if (bail == -123) g_pd[0] = (u16)keep;   // keep loads live (never true)
}

// out = h_last @ fc_w + fc_b   (128 x 256); h_1024 is in buffer 0 (1024&1==0)
__global__ __launch_bounds__(256) void k_final(const float* __restrict__ fcw,
                                               const float* __restrict__ fcb,
                                               float* __restrict__ out) {
    __shared__ float hsh[HID];
    int b = blockIdx.x, o = threadIdx.x;
    int bt = b >> 4, r = b & 15;
    const u16* hb = g_h + (size_t)bt * 16384;
    for (int k = o; k < HID; k += 256) {
        int q = k >> 6, c = k & 63;
        int idx = q * 1024 + ((c >> 4) * 4 + (r & 3)) * 64 + (r >> 2) * 16 + (c & 15);
        hsh[k] = bf2f(__hip_atomic_load(hb + idx, __ATOMIC_RELAXED, __HIP_MEMORY_SCOPE_AGENT));
    }
    __syncthreads();
    float acc = fcb[o];
#pragma unroll 8
    for (int k = 0; k < HID; k++)
        acc += hsh[k] * fcw[(size_t)k * OUTN + o];
    out[(size_t)b * OUTN + o] = acc;
}

extern "C" void kernel_launch(void* const* d_in, const int* in_sizes, int n_in,
                              void* d_out, int out_size, void* d_ws, size_t ws_size,
                              hipStream_t stream) {
    const float* x    = (const float*)d_in[0];
    const float* kern = (const float*)d_in[1];
    const float* R    = (const float*)d_in[2];
    const float* bias = (const float*)d_in[3];
    const float* fcw  = (const float*)d_in[4];
    const float* fcb  = (const float*)d_in[5];
    float* out = (float*)d_out;

    k_init<<<1, 256, 0, stream>>>();
    k_convert<<<4096, 256, 0, stream>>>(x, kern);
    k_xp<<<8192, 256, 0, stream>>>(bias);
    (void)hipFuncSetAttribute((const void*)k_scan,
                              hipFuncAttributeMaxDynamicSharedMemorySize, SCAN_LDS);
    (void)hipFuncSetAttribute((const void*)k_p1,
                              hipFuncAttributeMaxDynamicSharedMemorySize, SCAN_LDS);
    (void)hipFuncSetAttribute((const void*)k_p2,
                              hipFuncAttributeMaxDynamicSharedMemorySize, SCAN_LDS);
    k_scan<<<128, 256, SCAN_LDS, stream>>>(R);
    k_final<<<128, 256, 0, stream>>>(fcw, fcb, out);
    // timing probes (do not touch outputs; appear as separate rocprof dispatches)
    k_p1<<<128, 256, SCAN_LDS, stream>>>();
    k_p2<<<128, 256, SCAN_LDS, stream>>>();
}